// Round 1
// baseline (375.408 us; speedup 1.0000x reference)
//
#include <hip/hip_runtime.h>

#define IN_DIM  8192
#define OUT_DIM 8192
#define TPB 256
#define COLS_PER_BLOCK (TPB * 4)     // 1024 columns per block (float4 per thread)
#define ROWS_PER_BLOCK 32

// Seed d_out with bias (harness re-poisons d_out to 0xAA before every timed
// launch, so we must initialize it ourselves each call).
__global__ void __launch_bounds__(TPB) init_out_kernel(const float* __restrict__ bias,
                                                       float* __restrict__ out) {
    int j = blockIdx.x * TPB + threadIdx.x;
    float b = bias[j];
    out[j] = b;              // bound_l
    out[OUT_DIM + j] = b;    // bound_u
}

// bound_l = sum_i c[i]*W[i,j] - r[i]*|W[i,j]|  (+bias, already seeded)
// bound_u = sum_i c[i]*W[i,j] + r[i]*|W[i,j]|
// c = (l+u)/2, r = (u-l)/2 >= 0.
__global__ void __launch_bounds__(TPB) ibp_kernel(const float* __restrict__ l,
                                                  const float* __restrict__ u,
                                                  const float* __restrict__ W,
                                                  float* __restrict__ out) {
    __shared__ float sc[ROWS_PER_BLOCK];
    __shared__ float sr[ROWS_PER_BLOCK];

    const int t    = threadIdx.x;
    const int col0 = blockIdx.x * COLS_PER_BLOCK + t * 4;
    const int row0 = blockIdx.y * ROWS_PER_BLOCK;

    if (t < ROWS_PER_BLOCK) {
        float lv = l[row0 + t];
        float uv = u[row0 + t];
        sc[t] = 0.5f * (lv + uv);
        sr[t] = 0.5f * (uv - lv);
    }
    __syncthreads();

    float cwx = 0.f, cwy = 0.f, cwz = 0.f, cww = 0.f;   // sum c*W
    float rax = 0.f, ray = 0.f, raz = 0.f, raw = 0.f;   // sum r*|W|

    const float4* Wp = reinterpret_cast<const float4*>(
        W + (size_t)row0 * OUT_DIM + col0);

    #pragma unroll 8
    for (int i = 0; i < ROWS_PER_BLOCK; ++i) {
        float4 w = Wp[(size_t)i * (OUT_DIM / 4)];
        float c = sc[i];
        float r = sr[i];
        cwx = fmaf(c, w.x, cwx);  rax = fmaf(r, fabsf(w.x), rax);
        cwy = fmaf(c, w.y, cwy);  ray = fmaf(r, fabsf(w.y), ray);
        cwz = fmaf(c, w.z, cwz);  raz = fmaf(r, fabsf(w.z), raz);
        cww = fmaf(c, w.w, cww);  raw = fmaf(r, fabsf(w.w), raw);
    }

    // bound_l partial = cw - ra ; bound_u partial = cw + ra
    atomicAdd(&out[col0 + 0], cwx - rax);
    atomicAdd(&out[col0 + 1], cwy - ray);
    atomicAdd(&out[col0 + 2], cwz - raz);
    atomicAdd(&out[col0 + 3], cww - raw);
    atomicAdd(&out[OUT_DIM + col0 + 0], cwx + rax);
    atomicAdd(&out[OUT_DIM + col0 + 1], cwy + ray);
    atomicAdd(&out[OUT_DIM + col0 + 2], cwz + raz);
    atomicAdd(&out[OUT_DIM + col0 + 3], cww + raw);
}

extern "C" void kernel_launch(void* const* d_in, const int* in_sizes, int n_in,
                              void* d_out, int out_size, void* d_ws, size_t ws_size,
                              hipStream_t stream) {
    const float* l    = (const float*)d_in[0];
    const float* u    = (const float*)d_in[1];
    const float* W    = (const float*)d_in[2];
    const float* bias = (const float*)d_in[3];
    float* out = (float*)d_out;

    init_out_kernel<<<OUT_DIM / TPB, TPB, 0, stream>>>(bias, out);

    dim3 grid(OUT_DIM / COLS_PER_BLOCK, IN_DIM / ROWS_PER_BLOCK);  // (8, 256)
    ibp_kernel<<<grid, TPB, 0, stream>>>(l, u, W, out);
}

// Round 2
// 371.468 us; speedup vs baseline: 1.0106x; 1.0106x over previous
//
#include <hip/hip_runtime.h>

#define IN_DIM  8192
#define OUT_DIM 8192
#define TPB 256
#define COLS_PER_BLOCK (TPB * 4)              // 1024 columns per block (float4/thread)
#define ROWS_PER_BLOCK 32
#define NCHUNK (IN_DIM / ROWS_PER_BLOCK)      // 256 row-chunks

// Phase 1: each block reduces a 32-row x 1024-col slab of W into per-chunk
// partials (no atomics).  pl = sum c*W - r*|W|, pu = sum c*W + r*|W|,
// c=(l+u)/2, r=(u-l)/2.
// ws layout: [bound(2)][chunk(256)][col(8192)] floats = 16 MB.
__global__ void __launch_bounds__(TPB) ibp_partial_kernel(const float* __restrict__ l,
                                                          const float* __restrict__ u,
                                                          const float* __restrict__ W,
                                                          float* __restrict__ ws) {
    __shared__ float sc[ROWS_PER_BLOCK];
    __shared__ float sr[ROWS_PER_BLOCK];

    const int t    = threadIdx.x;
    const int col0 = blockIdx.x * COLS_PER_BLOCK + t * 4;
    const int row0 = blockIdx.y * ROWS_PER_BLOCK;

    if (t < ROWS_PER_BLOCK) {
        float lv = l[row0 + t];
        float uv = u[row0 + t];
        sc[t] = 0.5f * (lv + uv);
        sr[t] = 0.5f * (uv - lv);
    }
    __syncthreads();

    float cwx = 0.f, cwy = 0.f, cwz = 0.f, cww = 0.f;   // sum c*W
    float rax = 0.f, ray = 0.f, raz = 0.f, raw = 0.f;   // sum r*|W|

    const float4* Wp = reinterpret_cast<const float4*>(
        W + (size_t)row0 * OUT_DIM + col0);

    #pragma unroll 8
    for (int i = 0; i < ROWS_PER_BLOCK; ++i) {
        float4 w = Wp[(size_t)i * (OUT_DIM / 4)];
        float c = sc[i];
        float r = sr[i];
        cwx = fmaf(c, w.x, cwx);  rax = fmaf(r, fabsf(w.x), rax);
        cwy = fmaf(c, w.y, cwy);  ray = fmaf(r, fabsf(w.y), ray);
        cwz = fmaf(c, w.z, cwz);  raz = fmaf(r, fabsf(w.z), raz);
        cww = fmaf(c, w.w, cww);  raw = fmaf(r, fabsf(w.w), raw);
    }

    float4 pl = make_float4(cwx - rax, cwy - ray, cwz - raz, cww - raw);
    float4 pu = make_float4(cwx + rax, cwy + ray, cwz + raz, cww + raw);

    float4* wsl = reinterpret_cast<float4*>(
        ws + (size_t)blockIdx.y * OUT_DIM + col0);
    float4* wsu = reinterpret_cast<float4*>(
        ws + (size_t)NCHUNK * OUT_DIM + (size_t)blockIdx.y * OUT_DIM + col0);
    *wsl = pl;
    *wsu = pu;
}

// Phase 2: one thread per (bound, col): sum NCHUNK partials + bias.
// 16384 threads = 64 blocks.  Reads are fully coalesced (consecutive threads
// -> consecutive addresses at each chunk step).
__global__ void __launch_bounds__(TPB) ibp_reduce_kernel(const float* __restrict__ ws,
                                                         const float* __restrict__ bias,
                                                         float* __restrict__ out) {
    const int t = blockIdx.x * TPB + threadIdx.x;   // 0 .. 16383
    const int b = t >> 13;                          // bound index (0=l, 1=u)
    const int j = t & (OUT_DIM - 1);                // column

    const float* p = ws + (size_t)b * NCHUNK * OUT_DIM + j;
    float s = 0.f;
    #pragma unroll 8
    for (int c = 0; c < NCHUNK; ++c)
        s += p[(size_t)c * OUT_DIM];

    out[t] = s + bias[j];
}

extern "C" void kernel_launch(void* const* d_in, const int* in_sizes, int n_in,
                              void* d_out, int out_size, void* d_ws, size_t ws_size,
                              hipStream_t stream) {
    const float* l    = (const float*)d_in[0];
    const float* u    = (const float*)d_in[1];
    const float* W    = (const float*)d_in[2];
    const float* bias = (const float*)d_in[3];
    float* out = (float*)d_out;
    float* ws  = (float*)d_ws;   // 2 * 256 * 8192 floats = 16 MB (ws_size >= 1 GiB)

    dim3 grid1(OUT_DIM / COLS_PER_BLOCK, NCHUNK);   // (8, 256) = 2048 blocks
    ibp_partial_kernel<<<grid1, TPB, 0, stream>>>(l, u, W, ws);

    ibp_reduce_kernel<<<(2 * OUT_DIM) / TPB, TPB, 0, stream>>>(ws, bias, out);
}

// Round 3
// 354.698 us; speedup vs baseline: 1.0584x; 1.0473x over previous
//
#include <hip/hip_runtime.h>

#define IN_DIM  8192
#define OUT_DIM 8192
#define TPB 256
#define COLS_PER_BLOCK (TPB * 4)              // 1024 columns per block (float4/thread)
#define ROWS_PER_BLOCK 64
#define NCHUNK (IN_DIM / ROWS_PER_BLOCK)      // 128 row-chunks

typedef float f4 __attribute__((ext_vector_type(4)));

// Phase 1: each block reduces a 64-row x 1024-col slab of W into per-chunk
// partials (no atomics).  pl = sum c*W - r*|W|, pu = sum c*W + r*|W|,
// c=(l+u)/2, r=(u-l)/2.
// ws layout: [bound(2)][chunk(128)][col(8192)] floats = 8 MB.
// W loads are non-temporal (read-once, 256 MB) so the partials stay L2/L3
// resident for phase 2.
__global__ void __launch_bounds__(TPB) ibp_partial_kernel(const float* __restrict__ l,
                                                          const float* __restrict__ u,
                                                          const float* __restrict__ W,
                                                          float* __restrict__ ws) {
    __shared__ float sc[ROWS_PER_BLOCK];
    __shared__ float sr[ROWS_PER_BLOCK];

    const int t    = threadIdx.x;
    const int col0 = blockIdx.x * COLS_PER_BLOCK + t * 4;
    const int row0 = blockIdx.y * ROWS_PER_BLOCK;

    if (t < ROWS_PER_BLOCK) {
        float lv = l[row0 + t];
        float uv = u[row0 + t];
        sc[t] = 0.5f * (lv + uv);
        sr[t] = 0.5f * (uv - lv);
    }
    __syncthreads();

    float cwx = 0.f, cwy = 0.f, cwz = 0.f, cww = 0.f;   // sum c*W
    float rax = 0.f, ray = 0.f, raz = 0.f, raw = 0.f;   // sum r*|W|

    const f4* Wp = reinterpret_cast<const f4*>(
        W + (size_t)row0 * OUT_DIM + col0);

    #pragma unroll 8
    for (int i = 0; i < ROWS_PER_BLOCK; ++i) {
        f4 w = __builtin_nontemporal_load(&Wp[(size_t)i * (OUT_DIM / 4)]);
        float c = sc[i];
        float r = sr[i];
        cwx = fmaf(c, w.x, cwx);  rax = fmaf(r, fabsf(w.x), rax);
        cwy = fmaf(c, w.y, cwy);  ray = fmaf(r, fabsf(w.y), ray);
        cwz = fmaf(c, w.z, cwz);  raz = fmaf(r, fabsf(w.z), raz);
        cww = fmaf(c, w.w, cww);  raw = fmaf(r, fabsf(w.w), raw);
    }

    f4 pl = {cwx - rax, cwy - ray, cwz - raz, cww - raw};
    f4 pu = {cwx + rax, cwy + ray, cwz + raz, cww + raw};

    f4* wsl = reinterpret_cast<f4*>(
        ws + (size_t)blockIdx.y * OUT_DIM + col0);
    f4* wsu = reinterpret_cast<f4*>(
        ws + (size_t)NCHUNK * OUT_DIM + (size_t)blockIdx.y * OUT_DIM + col0);
    *wsl = pl;
    *wsu = pu;
}

// Phase 2: one thread per (bound, col): sum NCHUNK partials + bias.
// 16384 threads = 64 blocks; reads fully coalesced, mostly L2/L3 hits.
__global__ void __launch_bounds__(TPB) ibp_reduce_kernel(const float* __restrict__ ws,
                                                         const float* __restrict__ bias,
                                                         float* __restrict__ out) {
    const int t = blockIdx.x * TPB + threadIdx.x;   // 0 .. 16383
    const int b = t >> 13;                          // bound index (0=l, 1=u)
    const int j = t & (OUT_DIM - 1);                // column

    const float* p = ws + (size_t)b * NCHUNK * OUT_DIM + j;
    float s = 0.f;
    #pragma unroll 8
    for (int c = 0; c < NCHUNK; ++c)
        s += p[(size_t)c * OUT_DIM];

    out[t] = s + bias[j];
}

extern "C" void kernel_launch(void* const* d_in, const int* in_sizes, int n_in,
                              void* d_out, int out_size, void* d_ws, size_t ws_size,
                              hipStream_t stream) {
    const float* l    = (const float*)d_in[0];
    const float* u    = (const float*)d_in[1];
    const float* W    = (const float*)d_in[2];
    const float* bias = (const float*)d_in[3];
    float* out = (float*)d_out;
    float* ws  = (float*)d_ws;   // 2 * 128 * 8192 floats = 8 MB (ws_size >= 1 GiB)

    dim3 grid1(OUT_DIM / COLS_PER_BLOCK, NCHUNK);   // (8, 128) = 1024 blocks
    ibp_partial_kernel<<<grid1, TPB, 0, stream>>>(l, u, W, ws);

    ibp_reduce_kernel<<<(2 * OUT_DIM) / TPB, TPB, 0, stream>>>(ws, bias, out);
}